// Round 6
// baseline (3566.489 us; speedup 1.0000x reference)
//
#include <hip/hip_runtime.h>

#define EMB      128
#define N_NODES_ 50000
#define N_EDGES_ 800000
#define N_GRAPH_ 256
#define NLAYER_  5

typedef short short8 __attribute__((ext_vector_type(8)));
typedef float floatx4 __attribute__((ext_vector_type(4)));

__device__ __forceinline__ float silu_f(float x) {
    // fast: v_rcp-based division (1 ulp) — error << bf16 state rounding
    return __fdividef(x, 1.0f + __expf(-x));
}
__device__ __forceinline__ float bf2f(unsigned short h) {
    return __uint_as_float(((unsigned)h) << 16);
}
__device__ __forceinline__ unsigned short f2bf(float f) {
    unsigned u = __float_as_uint(f);
    unsigned r = 0x7FFFu + ((u >> 16) & 1u);
    return (unsigned short)((u + r) >> 16);
}

// ---------------------------------------------------------------------------
// Edge sort by row: histogram -> 1-block exclusive scan -> atomic scatter.
// ---------------------------------------------------------------------------
__global__ __launch_bounds__(256) void hist_kernel(
    const int* __restrict__ row, int* __restrict__ hist)
{
    const int e = blockIdx.x * 256 + threadIdx.x;
    if (e < N_EDGES_) atomicAdd(&hist[row[e]], 1);
}

__global__ __launch_bounds__(256) void scan_kernel(
    const int* __restrict__ hist, int* __restrict__ cursor)
{
    __shared__ int ssum[256];
    const int tid = threadIdx.x;
    const int chunk = (N_NODES_ + 255) / 256;      // 196
    const int base = tid * chunk;
    int s = 0;
    for (int i = 0; i < chunk; ++i) {
        const int idx = base + i;
        if (idx < N_NODES_) s += hist[idx];
    }
    ssum[tid] = s;
    __syncthreads();
    for (int off = 1; off < 256; off <<= 1) {
        const int t2 = (tid >= off) ? ssum[tid - off] : 0;
        __syncthreads();
        ssum[tid] += t2;
        __syncthreads();
    }
    int run = ssum[tid] - s;                       // exclusive prefix of chunk
    for (int i = 0; i < chunk; ++i) {
        const int idx = base + i;
        if (idx < N_NODES_) { cursor[idx] = run; run += hist[idx]; }
    }
}

__global__ __launch_bounds__(256) void scatter_kernel(
    const int* __restrict__ row, const int* __restrict__ col,
    int* __restrict__ cursor, int* __restrict__ row_s, int* __restrict__ col_s)
{
    const int e = blockIdx.x * 256 + threadIdx.x;
    if (e >= N_EDGES_) return;
    const int r = row[e];
    const int p = atomicAdd(&cursor[r], 1);
    row_s[p] = r;
    col_s[p] = col[e];
}

// ---------------------------------------------------------------------------
// Weight packing: fp32 [K][128] -> bf16 B-fragment order for 16x16x32 MFMA.
// ---------------------------------------------------------------------------
__global__ __launch_bounds__(256) void pack_w_kernel(
    const float* __restrict__ edge_w0, const float* __restrict__ edge_w,
    unsigned short* __restrict__ Wp)
{
    const int bid = blockIdx.x;            // 200 = 5 layers * 5 stages * 8 tiles
    const int l = bid / 40, r = bid % 40, s = r / 8, t = r % 8;
    const int Kb = (s == 0) ? 12 : 4;
    const float* __restrict__ src = (s == 0)
        ? edge_w0 + (size_t)l * 384 * 128
        : edge_w  + ((size_t)l * 4 + (s - 1)) * 128 * 128;
    unsigned short* __restrict__ dst =
        Wp + (size_t)l * 114688 + ((s == 0) ? 0 : (49152 + (s - 1) * 16384)) + (size_t)t * Kb * 512;
    const int n = Kb * 512;
    for (int p = threadIdx.x; p < n; p += 256) {
        const int j = p & 7, lane = (p >> 3) & 63, kb = p >> 9;
        const int k  = kb * 32 + ((lane >> 4) << 3) + j;
        const int nn = t * 16 + (lane & 15);
        dst[p] = f2bf(src[(size_t)k * 128 + nn]);
    }
}

// ---------------------------------------------------------------------------
// SORTED-edge MFMA edge MLP. Edges sorted by row -> phase-2 aggregation is a
// run-length segmented reduction (run boundaries wave-uniform), ~10x fewer
// atomics. Staging is pure bf16 copies (h_node_bf precomputed).
// ---------------------------------------------------------------------------
__global__ __launch_bounds__(256, 3) void edge_mlp_sorted_kernel(
    const unsigned short* __restrict__ h_node_bf, unsigned short* __restrict__ h_edge,
    float* __restrict__ agg,
    const int* __restrict__ row_s, const int* __restrict__ col_s,
    const unsigned short* __restrict__ Wp,
    const float* __restrict__ b0, const float* __restrict__ bh)
{
    __shared__ unsigned short A[64][392];      // 50,176 B
    __shared__ int rv[64], cv[64];
    const int tid = threadIdx.x;
    const int e0 = blockIdx.x * 64;

    if (tid < 64) { rv[tid] = row_s[e0 + tid]; cv[tid] = col_s[e0 + tid]; }
    __syncthreads();

    // staging: pure short8 copies, no conversion
    for (int idx = tid; idx < 64 * 48; idx += 256) {
        const int t  = idx / 48;
        const int k8 = (idx % 48) << 3;
        const unsigned short* src =
            (k8 < 128) ? &h_edge[(size_t)(e0 + t) * 128 + k8]
          : (k8 < 256) ? &h_node_bf[(size_t)rv[t] * 128 + (k8 - 128)]
                       : &h_node_bf[(size_t)cv[t] * 128 + (k8 - 256)];
        *(short8*)&A[t][k8] = *(const short8*)src;
    }
    __syncthreads();

    const int lane = tid & 63;
    const int wv   = tid >> 6;
    const int lr   = lane & 15;
    const int lg   = lane >> 4;
    const int nt0  = 2 * wv, nt1 = 2 * wv + 1;

    for (int s = 0; s < 5; ++s) {
        const int Kb = (s == 0) ? 12 : 4;
        const unsigned short* __restrict__ Ws =
            Wp + ((s == 0) ? 0 : (49152 + (s - 1) * 16384));
        const float* __restrict__ bias = (s == 0) ? b0 : (bh + (s - 1) * 128);

        floatx4 acc[4][2];
#pragma unroll
        for (int mt = 0; mt < 4; ++mt) {
            acc[mt][0] = (floatx4){0.f, 0.f, 0.f, 0.f};
            acc[mt][1] = (floatx4){0.f, 0.f, 0.f, 0.f};
        }
        const unsigned short* bptr0 = Ws + ((size_t)(nt0 * Kb) * 64 + lane) * 8;
        const unsigned short* bptr1 = Ws + ((size_t)(nt1 * Kb) * 64 + lane) * 8;
#pragma unroll 2
        for (int kb = 0; kb < Kb; ++kb) {
            const short8 bf0 = *(const short8*)(bptr0 + (size_t)kb * 512);
            const short8 bf1 = *(const short8*)(bptr1 + (size_t)kb * 512);
#pragma unroll
            for (int mt = 0; mt < 4; ++mt) {
                const short8 af = *(const short8*)&A[mt * 16 + lr][kb * 32 + lg * 8];
                acc[mt][0] = __builtin_amdgcn_mfma_f32_16x16x32_bf16(af, bf0, acc[mt][0], 0, 0, 0);
                acc[mt][1] = __builtin_amdgcn_mfma_f32_16x16x32_bf16(af, bf1, acc[mt][1], 0, 0, 0);
            }
        }
        const float bn0 = bias[nt0 * 16 + lr];
        const float bn1 = bias[nt1 * 16 + lr];
        __syncthreads();
#pragma unroll
        for (int mt = 0; mt < 4; ++mt)
#pragma unroll
            for (int r4 = 0; r4 < 4; ++r4) {
                const int m = mt * 16 + lg * 4 + r4;
                A[m][nt0 * 16 + lr] = f2bf(silu_f(acc[mt][0][r4] + bn0));
                A[m][nt1 * 16 + lr] = f2bf(silu_f(acc[mt][1][r4] + bn1));
            }
        __syncthreads();
    }

    // phase 1: h_edge_new = old + m; store global + back to LDS
    for (int idx = tid; idx < 64 * 16; idx += 256) {
        const int t  = idx >> 4;
        const int k8 = (idx & 15) << 3;
        const size_t eoff = (size_t)(e0 + t) * 128 + k8;
        const short8 mv = *(const short8*)&A[t][k8];
        const short8 ov = *(const short8*)&h_edge[eoff];
        short8 sv;
#pragma unroll
        for (int i = 0; i < 8; ++i)
            sv[i] = (short)f2bf(bf2f((unsigned short)ov[i]) + bf2f((unsigned short)mv[i]));
        *(short8*)&h_edge[eoff] = sv;
        *(short8*)&A[t][k8] = sv;
    }
    __syncthreads();

    // phase 2: run-length merged scatter atomics (rows sorted within block,
    // run boundaries uniform across the wave -> lane-consecutive flushes)
    {
        const int c    = tid & 127;
        const int half = tid >> 7;
        const int tstart = half * 32;
        int curRow = rv[tstart];
        float accv = 0.f;
#pragma unroll 8
        for (int t = tstart; t < tstart + 32; ++t) {
            const int rr = rv[t];
            const float v = bf2f(A[t][c]);
            if (rr != curRow) {
                atomicAdd(&agg[(size_t)curRow * 128 + c], accv);
                accv = 0.f;
                curRow = rr;
            }
            accv += v;
        }
        atomicAdd(&agg[(size_t)curRow * 128 + c], accv);
    }
}

// ---------------------------------------------------------------------------
// Round-5 MFMA edge MLP (unsorted, fp32 h_node staging) — ws fallback.
// ---------------------------------------------------------------------------
__global__ __launch_bounds__(256, 3) void edge_mlp_mfma_kernel(
    const float* __restrict__ h_node, unsigned short* __restrict__ h_edge,
    float* __restrict__ agg,
    const int* __restrict__ row, const int* __restrict__ col,
    const unsigned short* __restrict__ Wp,
    const float* __restrict__ b0, const float* __restrict__ bh)
{
    __shared__ unsigned short A[64][392];
    __shared__ int rv[64], cv[64];
    const int tid = threadIdx.x;
    const int e0 = blockIdx.x * 64;

    if (tid < 64) { rv[tid] = row[e0 + tid]; cv[tid] = col[e0 + tid]; }
    __syncthreads();

    for (int idx = tid; idx < 64 * 48; idx += 256) {
        const int t  = idx / 48;
        const int k8 = (idx % 48) << 3;
        if (k8 < 128) {
            *(short8*)&A[t][k8] = *(const short8*)&h_edge[(size_t)(e0 + t) * 128 + k8];
        } else {
            const float* src = (k8 < 256) ? &h_node[(size_t)rv[t] * 128 + (k8 - 128)]
                                          : &h_node[(size_t)cv[t] * 128 + (k8 - 256)];
            const float4 f0 = *(const float4*)src;
            const float4 f1 = *(const float4*)(src + 4);
            short8 v;
            v[0] = (short)f2bf(f0.x); v[1] = (short)f2bf(f0.y);
            v[2] = (short)f2bf(f0.z); v[3] = (short)f2bf(f0.w);
            v[4] = (short)f2bf(f1.x); v[5] = (short)f2bf(f1.y);
            v[6] = (short)f2bf(f1.z); v[7] = (short)f2bf(f1.w);
            *(short8*)&A[t][k8] = v;
        }
    }
    __syncthreads();

    const int lane = tid & 63;
    const int wv   = tid >> 6;
    const int lr   = lane & 15;
    const int lg   = lane >> 4;
    const int nt0  = 2 * wv, nt1 = 2 * wv + 1;

    for (int s = 0; s < 5; ++s) {
        const int Kb = (s == 0) ? 12 : 4;
        const unsigned short* __restrict__ Ws =
            Wp + ((s == 0) ? 0 : (49152 + (s - 1) * 16384));
        const float* __restrict__ bias = (s == 0) ? b0 : (bh + (s - 1) * 128);

        floatx4 acc[4][2];
#pragma unroll
        for (int mt = 0; mt < 4; ++mt) {
            acc[mt][0] = (floatx4){0.f, 0.f, 0.f, 0.f};
            acc[mt][1] = (floatx4){0.f, 0.f, 0.f, 0.f};
        }
        const unsigned short* bptr0 = Ws + ((size_t)(nt0 * Kb) * 64 + lane) * 8;
        const unsigned short* bptr1 = Ws + ((size_t)(nt1 * Kb) * 64 + lane) * 8;
#pragma unroll 2
        for (int kb = 0; kb < Kb; ++kb) {
            const short8 bf0 = *(const short8*)(bptr0 + (size_t)kb * 512);
            const short8 bf1 = *(const short8*)(bptr1 + (size_t)kb * 512);
#pragma unroll
            for (int mt = 0; mt < 4; ++mt) {
                const short8 af = *(const short8*)&A[mt * 16 + lr][kb * 32 + lg * 8];
                acc[mt][0] = __builtin_amdgcn_mfma_f32_16x16x32_bf16(af, bf0, acc[mt][0], 0, 0, 0);
                acc[mt][1] = __builtin_amdgcn_mfma_f32_16x16x32_bf16(af, bf1, acc[mt][1], 0, 0, 0);
            }
        }
        const float bn0 = bias[nt0 * 16 + lr];
        const float bn1 = bias[nt1 * 16 + lr];
        __syncthreads();
#pragma unroll
        for (int mt = 0; mt < 4; ++mt)
#pragma unroll
            for (int r4 = 0; r4 < 4; ++r4) {
                const int m = mt * 16 + lg * 4 + r4;
                A[m][nt0 * 16 + lr] = f2bf(silu_f(acc[mt][0][r4] + bn0));
                A[m][nt1 * 16 + lr] = f2bf(silu_f(acc[mt][1][r4] + bn1));
            }
        __syncthreads();
    }

    for (int idx = tid; idx < 64 * 16; idx += 256) {
        const int t  = idx >> 4;
        const int k8 = (idx & 15) << 3;
        const size_t eoff = (size_t)(e0 + t) * 128 + k8;
        const short8 mv = *(const short8*)&A[t][k8];
        const short8 ov = *(const short8*)&h_edge[eoff];
        short8 sv;
#pragma unroll
        for (int i = 0; i < 8; ++i)
            sv[i] = (short)f2bf(bf2f((unsigned short)ov[i]) + bf2f((unsigned short)mv[i]));
        *(short8*)&h_edge[eoff] = sv;
        *(short8*)&A[t][k8] = sv;
    }
    __syncthreads();

#pragma unroll 8
    for (int w = 0; w < 32; ++w) {
        const int g = w * 256 + tid;
        const int t = g >> 7;
        const int c = g & 127;
        atomicAdd(&agg[(size_t)rv[t] * 128 + c], bf2f(A[t][c]));
    }
}

// ---------------------------------------------------------------------------
// Generic [N,128] @ [128,128] (+bias, gather / silu / residual; optional
// bf16 shadow copy of the result for edge-kernel staging).
// ---------------------------------------------------------------------------
__device__ __forceinline__ void fma4x4(const float4 a[4], const float4& w0, const float4& w1,
                                       const float4& w2, const float4& w3, float acc[4][4]) {
#pragma unroll
    for (int i = 0; i < 4; ++i) {
        acc[i][0] = fmaf(a[i].x, w0.x, fmaf(a[i].y, w1.x, fmaf(a[i].z, w2.x, fmaf(a[i].w, w3.x, acc[i][0]))));
        acc[i][1] = fmaf(a[i].x, w0.y, fmaf(a[i].y, w1.y, fmaf(a[i].z, w2.y, fmaf(a[i].w, w3.y, acc[i][1]))));
        acc[i][2] = fmaf(a[i].x, w0.z, fmaf(a[i].y, w1.z, fmaf(a[i].z, w2.z, fmaf(a[i].w, w3.z, acc[i][2]))));
        acc[i][3] = fmaf(a[i].x, w0.w, fmaf(a[i].y, w1.w, fmaf(a[i].z, w2.w, fmaf(a[i].w, w3.w, acc[i][3]))));
    }
}

template <int GATHER, int RESID, int SILU, int WBF>
__global__ __launch_bounds__(256, 4) void row_gemm_kernel(
    const float* __restrict__ src, const int* __restrict__ gidx,
    const float* __restrict__ W, const float* __restrict__ bias,
    float* __restrict__ dst, unsigned short* __restrict__ dst_bf, int N)
{
    __shared__ __align__(16) float A[32][132];
    const int tid = threadIdx.x;
    const int n0 = blockIdx.x * 32;

    for (int idx = tid; idx < 32 * 32; idx += 256) {
        int t = idx >> 5, k = (idx & 31) << 2;
        int n = n0 + t;
        float4 v = make_float4(0.f, 0.f, 0.f, 0.f);
        if (n < N) {
            int rr = GATHER ? gidx[n] : n;
            v = *(const float4*)&src[(size_t)rr * 128 + k];
        }
        *(float4*)&A[t][k] = v;
    }
    __syncthreads();

    const int r = tid >> 5, c = tid & 31;
    const int t0 = r << 2, j0 = c << 2;
    float acc[4][4] = {{0.f, 0.f, 0.f, 0.f}};
#pragma unroll 2
    for (int kk = 0; kk < 128; kk += 4) {
        float4 a[4];
#pragma unroll
        for (int i = 0; i < 4; ++i) a[i] = *(const float4*)&A[t0 + i][kk];
        const float4 w0 = *(const float4*)&W[(size_t)(kk + 0) * 128 + j0];
        const float4 w1 = *(const float4*)&W[(size_t)(kk + 1) * 128 + j0];
        const float4 w2 = *(const float4*)&W[(size_t)(kk + 2) * 128 + j0];
        const float4 w3 = *(const float4*)&W[(size_t)(kk + 3) * 128 + j0];
        fma4x4(a, w0, w1, w2, w3, acc);
    }
    const float4 bv = *(const float4*)&bias[j0];
    const float bias4[4] = {bv.x, bv.y, bv.z, bv.w};
#pragma unroll
    for (int i = 0; i < 4; ++i) {
        int n = n0 + t0 + i;
        if (n >= N) continue;
        float x[4];
#pragma unroll
        for (int jj = 0; jj < 4; ++jj) {
            x[jj] = acc[i][jj] + bias4[jj];
            if (SILU) x[jj] = silu_f(x[jj]);
        }
        const size_t off = (size_t)n * 128 + j0;
        float4 o = make_float4(x[0], x[1], x[2], x[3]);
        if (RESID) {
            float4 d = *(const float4*)&dst[off];
            o.x += d.x; o.y += d.y; o.z += d.z; o.w += d.w;
        }
        *(float4*)&dst[off] = o;
        if (WBF)
            *(ushort4*)&dst_bf[off] = make_ushort4(f2bf(o.x), f2bf(o.y), f2bf(o.z), f2bf(o.w));
    }
}

// ---------------------------------------------------------------------------
// Edge embedding (works on sorted or unsorted edge lists).
// ---------------------------------------------------------------------------
__global__ __launch_bounds__(256) void edge_embed_kernel(
    const float* __restrict__ pos, const int* __restrict__ row, const int* __restrict__ col,
    const float* __restrict__ Wemb, const float* __restrict__ bemb,
    unsigned short* __restrict__ h_edge, int E)
{
    __shared__ __align__(16) float Ws[32][128];
    __shared__ float bas[8][32];
    const int tid = threadIdx.x;
    {
        const float4* Wv = (const float4*)Wemb;
        float4* Wsv = (float4*)Ws;
        for (int idx = tid; idx < 1024; idx += 256) Wsv[idx] = Wv[idx];
    }
    const int g = tid >> 5, k = tid & 31;
    const int j = tid & 127, gh = tid >> 7;
    const float mu   = (float)k * (5.0f / 31.0f);
    const float invs = 32.0f / 5.0f;

    for (int eb = blockIdx.x * 8; eb < E; eb += gridDim.x * 8) {
        __syncthreads();
        const int e = eb + g;
        const int rr = row[e], cc = col[e];
        const float dx = pos[rr * 3 + 0] - pos[cc * 3 + 0];
        const float dy = pos[rr * 3 + 1] - pos[cc * 3 + 1];
        const float dz = pos[rr * 3 + 2] - pos[cc * 3 + 2];
        const float d = sqrtf(dx * dx + dy * dy + dz * dz);
        const float t = (d - mu) * invs;
        bas[g][k] = __expf(-0.5f * t * t);
        __syncthreads();
#pragma unroll
        for (int gg = 0; gg < 4; ++gg) {
            const int ge = (gh << 2) + gg;
            float h = bemb[j];
#pragma unroll
            for (int kk = 0; kk < 32; ++kk) h = fmaf(bas[ge][kk], Ws[kk][j], h);
            h_edge[(size_t)(eb + ge) * 128 + j] = f2bf(h);
        }
    }
}

// ---------------------------------------------------------------------------
// Graph pooling + output head.
// ---------------------------------------------------------------------------
__global__ __launch_bounds__(128) void pool_kernel(
    const float* __restrict__ h_node, const int* __restrict__ batch,
    float* __restrict__ sums, float* __restrict__ cnt, int N)
{
    __shared__ int bb[256];
    const int tid = threadIdx.x;
    const int n0 = blockIdx.x * 256;
    for (int idx = tid; idx < 256; idx += 128) {
        int n = n0 + idx;
        bb[idx] = (n < N) ? batch[n] : -1;
    }
    __syncthreads();
    int cur = bb[0];
    float run = 0.f, runc = 0.f;
    for (int i = 0; i < 256; ++i) {
        const int b = bb[i];
        if (b < 0) break;
        if (b != cur) {
            atomicAdd(&sums[(size_t)cur * 128 + tid], run);
            if (tid == 0) atomicAdd(&cnt[cur], runc);
            run = 0.f; runc = 0.f; cur = b;
        }
        run += h_node[(size_t)(n0 + i) * 128 + tid];
        runc += 1.f;
    }
    atomicAdd(&sums[(size_t)cur * 128 + tid], run);
    if (tid == 0) atomicAdd(&cnt[cur], runc);
}

__global__ __launch_bounds__(256) void final_kernel(
    const float* __restrict__ sums, const float* __restrict__ cnt,
    const float* __restrict__ out_w, const float* __restrict__ out_b,
    float* __restrict__ out)
{
    const int g = threadIdx.x;
    const float c = fmaxf(cnt[g], 1.0f);
    float acc = 0.f;
    for (int jj = 0; jj < 128; ++jj) acc = fmaf(sums[(size_t)g * 128 + jj], out_w[jj], acc);
    out[g] = acc / c + out_b[0];
}

__global__ void zero_out_kernel(float* out, int n) {
    int i = blockIdx.x * 256 + threadIdx.x;
    if (i < n) out[i] = 0.f;
}

// ---------------------------------------------------------------------------

extern "C" void kernel_launch(void* const* d_in, const int* in_sizes, int n_in,
                              void* d_out, int out_size, void* d_ws, size_t ws_size,
                              hipStream_t stream)
{
    const int*   z          = (const int*)  d_in[0];
    const float* pos        = (const float*)d_in[1];
    const int*   batch      = (const int*)  d_in[2];
    const int*   eidx       = (const int*)  d_in[3];
    const float* atom_table = (const float*)d_in[4];
    const float* atom_w     = (const float*)d_in[5];
    const float* atom_b     = (const float*)d_in[6];
    const float* edge_emb_w = (const float*)d_in[7];
    const float* edge_emb_b = (const float*)d_in[8];
    const float* edge_w0    = (const float*)d_in[9];
    const float* edge_b0    = (const float*)d_in[10];
    const float* edge_w     = (const float*)d_in[11];
    const float* edge_b     = (const float*)d_in[12];
    const float* node_w     = (const float*)d_in[13];
    const float* node_b     = (const float*)d_in[14];
    const float* out_w      = (const float*)d_in[15];
    const float* out_b      = (const float*)d_in[16];
    const int* row = eidx;
    const int* col = eidx + N_EDGES_;

    // ws layout
    float* ws     = (float*)d_ws;
    float* h_node = ws;                                         // 6.4M f32
    float* aggb   = h_node + (size_t)N_NODES_ * EMB;            // 6.4M f32
    float* sums   = aggb   + (size_t)N_NODES_ * EMB;            // 32768 f32
    float* cnt    = sums   + (size_t)N_GRAPH_ * EMB;            // 256 f32
    unsigned short* h_node_bf = (unsigned short*)(cnt + N_GRAPH_);      // 6.4M bf16
    unsigned short* h_edge    = h_node_bf + (size_t)N_NODES_ * EMB;     // 102.4M bf16
    unsigned short* Wp        = h_edge + (size_t)N_EDGES_ * EMB;        // 573440 bf16
    int* hist   = (int*)(Wp + (size_t)NLAYER_ * 114688);                // 50000 int
    int* cursor = hist + N_NODES_;                                      // 50000 int
    int* row_s  = cursor + N_NODES_;                                    // 800000 int
    int* col_s  = row_s + N_EDGES_;                                     // 800000 int

    const size_t headA       = ((size_t)N_NODES_ * EMB * 2 + (size_t)N_GRAPH_ * EMB + N_GRAPH_) * 4;
    const size_t need_mfma   = headA + (size_t)N_EDGES_ * EMB * 2 + (size_t)NLAYER_ * 114688 * 2;
    const size_t need_sorted = need_mfma + (size_t)N_NODES_ * EMB * 2   // h_node_bf
                             + (size_t)N_NODES_ * 2 * 4                 // hist+cursor
                             + (size_t)N_EDGES_ * 2 * 4;                // row_s+col_s

    if (ws_size < need_mfma) {
        zero_out_kernel<<<1, 256, 0, stream>>>((float*)d_out, N_GRAPH_);
        return;
    }
    const bool sorted_path = (ws_size >= need_sorted);
    const int grid_rows = (N_NODES_ + 31) / 32;

    if (sorted_path) {
        // NOTE: for sorted path, h_node_bf sits between cnt and h_edge; but in
        // the fallback layout h_edge starts right after cnt — recompute:
        (void)hipMemsetAsync(hist, 0, N_NODES_ * sizeof(int), stream);
        hist_kernel<<<(N_EDGES_ + 255) / 256, 256, 0, stream>>>(row, hist);
        scan_kernel<<<1, 256, 0, stream>>>(hist, cursor);
        scatter_kernel<<<(N_EDGES_ + 255) / 256, 256, 0, stream>>>(row, col, cursor, row_s, col_s);

        row_gemm_kernel<1, 0, 0, 1><<<grid_rows, 256, 0, stream>>>(
            atom_table, z, atom_w, atom_b, h_node, h_node_bf, N_NODES_);
        edge_embed_kernel<<<1024, 256, 0, stream>>>(pos, row_s, col_s, edge_emb_w, edge_emb_b, h_edge, N_EDGES_);
        pack_w_kernel<<<200, 256, 0, stream>>>(edge_w0, edge_w, Wp);

        for (int l = 0; l < NLAYER_; ++l) {
            (void)hipMemsetAsync(aggb, 0, (size_t)N_NODES_ * EMB * sizeof(float), stream);
            edge_mlp_sorted_kernel<<<N_EDGES_ / 64, 256, 0, stream>>>(
                h_node_bf, h_edge, aggb, row_s, col_s,
                Wp + (size_t)l * 114688,
                edge_b0 + (size_t)l * 128, edge_b + (size_t)l * 4 * 128);
            row_gemm_kernel<0, 1, 1, 1><<<grid_rows, 256, 0, stream>>>(
                aggb, nullptr, node_w + (size_t)l * 128 * 128, node_b + (size_t)l * 128,
                h_node, h_node_bf, N_NODES_);
        }
    } else {
        // fallback (round-5 path): h_edge directly after cnt, no bf16 h_node
        unsigned short* h_edge_f = (unsigned short*)(cnt + N_GRAPH_);
        unsigned short* Wp_f     = h_edge_f + (size_t)N_EDGES_ * EMB;

        row_gemm_kernel<1, 0, 0, 0><<<grid_rows, 256, 0, stream>>>(
            atom_table, z, atom_w, atom_b, h_node, nullptr, N_NODES_);
        edge_embed_kernel<<<1024, 256, 0, stream>>>(pos, row, col, edge_emb_w, edge_emb_b, h_edge_f, N_EDGES_);
        pack_w_kernel<<<200, 256, 0, stream>>>(edge_w0, edge_w, Wp_f);

        for (int l = 0; l < NLAYER_; ++l) {
            (void)hipMemsetAsync(aggb, 0, (size_t)N_NODES_ * EMB * sizeof(float), stream);
            edge_mlp_mfma_kernel<<<N_EDGES_ / 64, 256, 0, stream>>>(
                h_node, h_edge_f, aggb, row, col,
                Wp_f + (size_t)l * 114688,
                edge_b0 + (size_t)l * 128, edge_b + (size_t)l * 4 * 128);
            row_gemm_kernel<0, 1, 1, 0><<<grid_rows, 256, 0, stream>>>(
                aggb, nullptr, node_w + (size_t)l * 128 * 128, node_b + (size_t)l * 128,
                h_node, nullptr, N_NODES_);
        }
    }

    (void)hipMemsetAsync(sums, 0, ((size_t)N_GRAPH_ * EMB + N_GRAPH_) * sizeof(float), stream);
    pool_kernel<<<(N_NODES_ + 255) / 256, 128, 0, stream>>>(h_node, batch, sums, cnt, N_NODES_);
    final_kernel<<<1, 256, 0, stream>>>(sums, cnt, out_w, out_b, (float*)d_out);
}

// Round 7
// 3239.669 us; speedup vs baseline: 1.1009x; 1.1009x over previous
//
#include <hip/hip_runtime.h>

#define EMB      128
#define N_NODES_ 50000
#define N_EDGES_ 800000
#define N_GRAPH_ 256
#define NLAYER_  5

typedef short short8 __attribute__((ext_vector_type(8)));
typedef float floatx4 __attribute__((ext_vector_type(4)));

__device__ __forceinline__ float silu_f(float x) {
    return __fdividef(x, 1.0f + __expf(-x));   // rcp-based; err << bf16 rounding
}
__device__ __forceinline__ float bf2f(unsigned short h) {
    return __uint_as_float(((unsigned)h) << 16);
}
__device__ __forceinline__ unsigned short f2bf(float f) {
    unsigned u = __float_as_uint(f);
    unsigned r = 0x7FFFu + ((u >> 16) & 1u);
    return (unsigned short)((u + r) >> 16);
}

// ---------------------------------------------------------------------------
// Edge sort by destination row: histogram -> 1-block scan -> atomic scatter.
// ---------------------------------------------------------------------------
__global__ __launch_bounds__(256) void hist_kernel(
    const int* __restrict__ row, int* __restrict__ hist)
{
    const int e = blockIdx.x * 256 + threadIdx.x;
    if (e < N_EDGES_) atomicAdd(&hist[row[e]], 1);
}

__global__ __launch_bounds__(256) void scan_kernel(
    const int* __restrict__ hist, int* __restrict__ cursor)
{
    __shared__ int ssum[256];
    const int tid = threadIdx.x;
    const int chunk = (N_NODES_ + 255) / 256;      // 196
    const int base = tid * chunk;
    int s = 0;
    for (int i = 0; i < chunk; ++i) {
        const int idx = base + i;
        if (idx < N_NODES_) s += hist[idx];
    }
    ssum[tid] = s;
    __syncthreads();
    for (int off = 1; off < 256; off <<= 1) {
        const int t2 = (tid >= off) ? ssum[tid - off] : 0;
        __syncthreads();
        ssum[tid] += t2;
        __syncthreads();
    }
    int run = ssum[tid] - s;                       // exclusive prefix
    for (int i = 0; i < chunk; ++i) {
        const int idx = base + i;
        if (idx < N_NODES_) { cursor[idx] = run; run += hist[idx]; }
    }
}

__global__ __launch_bounds__(256) void scatter_kernel(
    const int* __restrict__ row, const int* __restrict__ col,
    int* __restrict__ cursor, int* __restrict__ row_s, int* __restrict__ col_s)
{
    const int e = blockIdx.x * 256 + threadIdx.x;
    if (e >= N_EDGES_) return;
    const int r = row[e];
    const int p = atomicAdd(&cursor[r], 1);
    row_s[p] = r;
    col_s[p] = col[e];
}

// ---------------------------------------------------------------------------
// Weight packing: fp32 [K][128] -> bf16 B-fragment order for 16x16x32 MFMA.
// ---------------------------------------------------------------------------
__global__ __launch_bounds__(256) void pack_w_kernel(
    const float* __restrict__ edge_w0, const float* __restrict__ edge_w,
    unsigned short* __restrict__ Wp)
{
    const int bid = blockIdx.x;            // 200 = 5 layers * 5 stages * 8 tiles
    const int l = bid / 40, r = bid % 40, s = r / 8, t = r % 8;
    const int Kb = (s == 0) ? 12 : 4;
    const float* __restrict__ src = (s == 0)
        ? edge_w0 + (size_t)l * 384 * 128
        : edge_w  + ((size_t)l * 4 + (s - 1)) * 128 * 128;
    unsigned short* __restrict__ dst =
        Wp + (size_t)l * 114688 + ((s == 0) ? 0 : (49152 + (s - 1) * 16384)) + (size_t)t * Kb * 512;
    const int n = Kb * 512;
    for (int p = threadIdx.x; p < n; p += 256) {
        const int j = p & 7, lane = (p >> 3) & 63, kb = p >> 9;
        const int k  = kb * 32 + ((lane >> 4) << 3) + j;
        const int nn = t * 16 + (lane & 15);
        dst[p] = f2bf(src[(size_t)k * 128 + nn]);
    }
}

// ---------------------------------------------------------------------------
// SORTED-edge MFMA edge MLP. Rows sorted -> phase-2 aggregation is a
// run-length merged scatter (run boundaries wave-uniform; flushes are
// lane-consecutive -> 16 lanes / 64B line). Staging = pure bf16 copies.
// ---------------------------------------------------------------------------
__global__ __launch_bounds__(256, 3) void edge_mlp_sorted_kernel(
    const unsigned short* __restrict__ h_node_bf, unsigned short* __restrict__ h_edge,
    float* __restrict__ agg,
    const int* __restrict__ row_s, const int* __restrict__ col_s,
    const unsigned short* __restrict__ Wp,
    const float* __restrict__ b0, const float* __restrict__ bh)
{
    __shared__ unsigned short A[64][392];      // 50,176 B
    __shared__ int rv[64], cv[64];
    const int tid = threadIdx.x;
    const int e0 = blockIdx.x * 64;

    if (tid < 64) { rv[tid] = row_s[e0 + tid]; cv[tid] = col_s[e0 + tid]; }
    __syncthreads();

    // staging: pure short8 copies, no conversion
    for (int idx = tid; idx < 64 * 48; idx += 256) {
        const int t  = idx / 48;
        const int k8 = (idx % 48) << 3;
        const unsigned short* src =
            (k8 < 128) ? &h_edge[(size_t)(e0 + t) * 128 + k8]
          : (k8 < 256) ? &h_node_bf[(size_t)rv[t] * 128 + (k8 - 128)]
                       : &h_node_bf[(size_t)cv[t] * 128 + (k8 - 256)];
        *(short8*)&A[t][k8] = *(const short8*)src;
    }
    __syncthreads();

    const int lane = tid & 63;
    const int wv   = tid >> 6;
    const int lr   = lane & 15;
    const int lg   = lane >> 4;
    const int nt0  = 2 * wv, nt1 = 2 * wv + 1;

    for (int s = 0; s < 5; ++s) {
        const int Kb = (s == 0) ? 12 : 4;
        const unsigned short* __restrict__ Ws =
            Wp + ((s == 0) ? 0 : (49152 + (s - 1) * 16384));
        const float* __restrict__ bias = (s == 0) ? b0 : (bh + (s - 1) * 128);

        floatx4 acc[4][2];
#pragma unroll
        for (int mt = 0; mt < 4; ++mt) {
            acc[mt][0] = (floatx4){0.f, 0.f, 0.f, 0.f};
            acc[mt][1] = (floatx4){0.f, 0.f, 0.f, 0.f};
        }
        const unsigned short* bptr0 = Ws + ((size_t)(nt0 * Kb) * 64 + lane) * 8;
        const unsigned short* bptr1 = Ws + ((size_t)(nt1 * Kb) * 64 + lane) * 8;
#pragma unroll 2
        for (int kb = 0; kb < Kb; ++kb) {
            const short8 bf0 = *(const short8*)(bptr0 + (size_t)kb * 512);
            const short8 bf1 = *(const short8*)(bptr1 + (size_t)kb * 512);
#pragma unroll
            for (int mt = 0; mt < 4; ++mt) {
                const short8 af = *(const short8*)&A[mt * 16 + lr][kb * 32 + lg * 8];
                acc[mt][0] = __builtin_amdgcn_mfma_f32_16x16x32_bf16(af, bf0, acc[mt][0], 0, 0, 0);
                acc[mt][1] = __builtin_amdgcn_mfma_f32_16x16x32_bf16(af, bf1, acc[mt][1], 0, 0, 0);
            }
        }
        const float bn0 = bias[nt0 * 16 + lr];
        const float bn1 = bias[nt1 * 16 + lr];
        __syncthreads();
#pragma unroll
        for (int mt = 0; mt < 4; ++mt)
#pragma unroll
            for (int r4 = 0; r4 < 4; ++r4) {
                const int m = mt * 16 + lg * 4 + r4;
                A[m][nt0 * 16 + lr] = f2bf(silu_f(acc[mt][0][r4] + bn0));
                A[m][nt1 * 16 + lr] = f2bf(silu_f(acc[mt][1][r4] + bn1));
            }
        __syncthreads();
    }

    // phase 1: h_edge_new = old + m; store global + back to LDS
    for (int idx = tid; idx < 64 * 16; idx += 256) {
        const int t  = idx >> 4;
        const int k8 = (idx & 15) << 3;
        const size_t eoff = (size_t)(e0 + t) * 128 + k8;
        const short8 mv = *(const short8*)&A[t][k8];
        const short8 ov = *(const short8*)&h_edge[eoff];
        short8 sv;
#pragma unroll
        for (int i = 0; i < 8; ++i)
            sv[i] = (short)f2bf(bf2f((unsigned short)ov[i]) + bf2f((unsigned short)mv[i]));
        *(short8*)&h_edge[eoff] = sv;
        *(short8*)&A[t][k8] = sv;
    }
    __syncthreads();

    // phase 2: run-length merged scatter atomics
    {
        const int c    = tid & 127;
        const int half = tid >> 7;
        const int tstart = half * 32;
        int curRow = rv[tstart];
        float accv = 0.f;
#pragma unroll 8
        for (int t = tstart; t < tstart + 32; ++t) {
            const int rr = rv[t];
            const float v = bf2f(A[t][c]);
            if (rr != curRow) {
                atomicAdd(&agg[(size_t)curRow * 128 + c], accv);
                accv = 0.f;
                curRow = rr;
            }
            accv += v;
        }
        atomicAdd(&agg[(size_t)curRow * 128 + c], accv);
    }
}

// ---------------------------------------------------------------------------
// Row GEMM with bf16 node state: dst is bf16; optional gather / silu /
// residual (residual read from bf16 dst).
// ---------------------------------------------------------------------------
__device__ __forceinline__ void fma4x4(const float4 a[4], const float4& w0, const float4& w1,
                                       const float4& w2, const float4& w3, float acc[4][4]) {
#pragma unroll
    for (int i = 0; i < 4; ++i) {
        acc[i][0] = fmaf(a[i].x, w0.x, fmaf(a[i].y, w1.x, fmaf(a[i].z, w2.x, fmaf(a[i].w, w3.x, acc[i][0]))));
        acc[i][1] = fmaf(a[i].x, w0.y, fmaf(a[i].y, w1.y, fmaf(a[i].z, w2.y, fmaf(a[i].w, w3.y, acc[i][1]))));
        acc[i][2] = fmaf(a[i].x, w0.z, fmaf(a[i].y, w1.z, fmaf(a[i].z, w2.z, fmaf(a[i].w, w3.z, acc[i][2]))));
        acc[i][3] = fmaf(a[i].x, w0.w, fmaf(a[i].y, w1.w, fmaf(a[i].z, w2.w, fmaf(a[i].w, w3.w, acc[i][3]))));
    }
}

template <int GATHER, int RESID, int SILU>
__global__ __launch_bounds__(256, 4) void row_gemm_bf_kernel(
    const float* __restrict__ src, const int* __restrict__ gidx,
    const float* __restrict__ W, const float* __restrict__ bias,
    unsigned short* __restrict__ dst, int N)
{
    __shared__ __align__(16) float A[32][132];
    const int tid = threadIdx.x;
    const int n0 = blockIdx.x * 32;

    for (int idx = tid; idx < 32 * 32; idx += 256) {
        int t = idx >> 5, k = (idx & 31) << 2;
        int n = n0 + t;
        float4 v = make_float4(0.f, 0.f, 0.f, 0.f);
        if (n < N) {
            int rr = GATHER ? gidx[n] : n;
            v = *(const float4*)&src[(size_t)rr * 128 + k];
        }
        *(float4*)&A[t][k] = v;
    }
    __syncthreads();

    const int r = tid >> 5, c = tid & 31;
    const int t0 = r << 2, j0 = c << 2;
    float acc[4][4] = {{0.f, 0.f, 0.f, 0.f}};
#pragma unroll 2
    for (int kk = 0; kk < 128; kk += 4) {
        float4 a[4];
#pragma unroll
        for (int i = 0; i < 4; ++i) a[i] = *(const float4*)&A[t0 + i][kk];
        const float4 w0 = *(const float4*)&W[(size_t)(kk + 0) * 128 + j0];
        const float4 w1 = *(const float4*)&W[(size_t)(kk + 1) * 128 + j0];
        const float4 w2 = *(const float4*)&W[(size_t)(kk + 2) * 128 + j0];
        const float4 w3 = *(const float4*)&W[(size_t)(kk + 3) * 128 + j0];
        fma4x4(a, w0, w1, w2, w3, acc);
    }
    const float4 bv = *(const float4*)&bias[j0];
    const float bias4[4] = {bv.x, bv.y, bv.z, bv.w};
#pragma unroll
    for (int i = 0; i < 4; ++i) {
        int n = n0 + t0 + i;
        if (n >= N) continue;
        float x[4];
#pragma unroll
        for (int jj = 0; jj < 4; ++jj) {
            x[jj] = acc[i][jj] + bias4[jj];
            if (SILU) x[jj] = silu_f(x[jj]);
        }
        const size_t off = (size_t)n * 128 + j0;
        if (RESID) {
            const ushort4 d = *(const ushort4*)&dst[off];
            x[0] += bf2f(d.x); x[1] += bf2f(d.y); x[2] += bf2f(d.z); x[3] += bf2f(d.w);
        }
        *(ushort4*)&dst[off] = make_ushort4(f2bf(x[0]), f2bf(x[1]), f2bf(x[2]), f2bf(x[3]));
    }
}

// ---------------------------------------------------------------------------
// Edge embedding (on sorted edge lists).
// ---------------------------------------------------------------------------
__global__ __launch_bounds__(256) void edge_embed_kernel(
    const float* __restrict__ pos, const int* __restrict__ row, const int* __restrict__ col,
    const float* __restrict__ Wemb, const float* __restrict__ bemb,
    unsigned short* __restrict__ h_edge, int E)
{
    __shared__ __align__(16) float Ws[32][128];
    __shared__ float bas[8][32];
    const int tid = threadIdx.x;
    {
        const float4* Wv = (const float4*)Wemb;
        float4* Wsv = (float4*)Ws;
        for (int idx = tid; idx < 1024; idx += 256) Wsv[idx] = Wv[idx];
    }
    const int g = tid >> 5, k = tid & 31;
    const int j = tid & 127, gh = tid >> 7;
    const float mu   = (float)k * (5.0f / 31.0f);
    const float invs = 32.0f / 5.0f;

    for (int eb = blockIdx.x * 8; eb < E; eb += gridDim.x * 8) {
        __syncthreads();
        const int e = eb + g;
        const int rr = row[e], cc = col[e];
        const float dx = pos[rr * 3 + 0] - pos[cc * 3 + 0];
        const float dy = pos[rr * 3 + 1] - pos[cc * 3 + 1];
        const float dz = pos[rr * 3 + 2] - pos[cc * 3 + 2];
        const float d = sqrtf(dx * dx + dy * dy + dz * dz);
        const float t = (d - mu) * invs;
        bas[g][k] = __expf(-0.5f * t * t);
        __syncthreads();
#pragma unroll
        for (int gg = 0; gg < 4; ++gg) {
            const int ge = (gh << 2) + gg;
            float h = bemb[j];
#pragma unroll
            for (int kk = 0; kk < 32; ++kk) h = fmaf(bas[ge][kk], Ws[kk][j], h);
            h_edge[(size_t)(eb + ge) * 128 + j] = f2bf(h);
        }
    }
}

// ---------------------------------------------------------------------------
// Graph pooling (bf16 node state) + output head.
// ---------------------------------------------------------------------------
__global__ __launch_bounds__(128) void pool_kernel(
    const unsigned short* __restrict__ h_node_bf, const int* __restrict__ batch,
    float* __restrict__ sums, float* __restrict__ cnt, int N)
{
    __shared__ int bb[256];
    const int tid = threadIdx.x;
    const int n0 = blockIdx.x * 256;
    for (int idx = tid; idx < 256; idx += 128) {
        int n = n0 + idx;
        bb[idx] = (n < N) ? batch[n] : -1;
    }
    __syncthreads();
    int cur = bb[0];
    float run = 0.f, runc = 0.f;
    for (int i = 0; i < 256; ++i) {
        const int b = bb[i];
        if (b < 0) break;
        if (b != cur) {
            atomicAdd(&sums[(size_t)cur * 128 + tid], run);
            if (tid == 0) atomicAdd(&cnt[cur], runc);
            run = 0.f; runc = 0.f; cur = b;
        }
        run += bf2f(h_node_bf[(size_t)(n0 + i) * 128 + tid]);
        runc += 1.f;
    }
    atomicAdd(&sums[(size_t)cur * 128 + tid], run);
    if (tid == 0) atomicAdd(&cnt[cur], runc);
}

__global__ __launch_bounds__(256) void final_kernel(
    const float* __restrict__ sums, const float* __restrict__ cnt,
    const float* __restrict__ out_w, const float* __restrict__ out_b,
    float* __restrict__ out)
{
    const int g = threadIdx.x;
    const float c = fmaxf(cnt[g], 1.0f);
    float acc = 0.f;
    for (int jj = 0; jj < 128; ++jj) acc = fmaf(sums[(size_t)g * 128 + jj], out_w[jj], acc);
    out[g] = acc / c + out_b[0];
}

__global__ void zero_out_kernel(float* out, int n) {
    int i = blockIdx.x * 256 + threadIdx.x;
    if (i < n) out[i] = 0.f;
}

// ---------------------------------------------------------------------------

extern "C" void kernel_launch(void* const* d_in, const int* in_sizes, int n_in,
                              void* d_out, int out_size, void* d_ws, size_t ws_size,
                              hipStream_t stream)
{
    const int*   z          = (const int*)  d_in[0];
    const float* pos        = (const float*)d_in[1];
    const int*   batch      = (const int*)  d_in[2];
    const int*   eidx       = (const int*)  d_in[3];
    const float* atom_table = (const float*)d_in[4];
    const float* atom_w     = (const float*)d_in[5];
    const float* atom_b     = (const float*)d_in[6];
    const float* edge_emb_w = (const float*)d_in[7];
    const float* edge_emb_b = (const float*)d_in[8];
    const float* edge_w0    = (const float*)d_in[9];
    const float* edge_b0    = (const float*)d_in[10];
    const float* edge_w     = (const float*)d_in[11];
    const float* edge_b     = (const float*)d_in[12];
    const float* node_w     = (const float*)d_in[13];
    const float* node_b     = (const float*)d_in[14];
    const float* out_w      = (const float*)d_in[15];
    const float* out_b      = (const float*)d_in[16];
    const int* row = eidx;
    const int* col = eidx + N_EDGES_;

    // ws layout (bf16 node state; fits in 251.28 MB — ws is known >= 257.3 MB):
    // agg f32 | sums f32 | cnt f32 | h_node bf16 | h_edge bf16 | Wp bf16 |
    // hist | cursor | row_s | col_s
    float* aggb = (float*)d_ws;                                         // 25.6 MB
    float* sums = aggb + (size_t)N_NODES_ * EMB;                        // 128 KB
    float* cnt  = sums + (size_t)N_GRAPH_ * EMB;                        // 1 KB
    unsigned short* h_node_bf = (unsigned short*)(cnt + N_GRAPH_);      // 12.8 MB
    unsigned short* h_edge    = h_node_bf + (size_t)N_NODES_ * EMB;     // 204.8 MB
    unsigned short* Wp        = h_edge + (size_t)N_EDGES_ * EMB;        // 1.15 MB
    int* hist   = (int*)(Wp + (size_t)NLAYER_ * 114688);                // 200 KB
    int* cursor = hist + N_NODES_;                                      // 200 KB
    int* row_s  = cursor + N_NODES_;                                    // 3.2 MB
    int* col_s  = row_s + N_EDGES_;                                     // 3.2 MB

    const size_t need = ((size_t)(N_NODES_ * EMB + N_GRAPH_ * EMB + N_GRAPH_)) * 4
                      + ((size_t)N_NODES_ * EMB + (size_t)N_EDGES_ * EMB + (size_t)NLAYER_ * 114688) * 2
                      + ((size_t)N_NODES_ * 2 + (size_t)N_EDGES_ * 2) * 4;   // 251,278,976

    if (ws_size < need) {
        zero_out_kernel<<<1, 256, 0, stream>>>((float*)d_out, N_GRAPH_);
        return;
    }

    const int grid_rows = (N_NODES_ + 31) / 32;

    // sort edges by destination row
    (void)hipMemsetAsync(hist, 0, N_NODES_ * sizeof(int), stream);
    hist_kernel<<<(N_EDGES_ + 255) / 256, 256, 0, stream>>>(row, hist);
    scan_kernel<<<1, 256, 0, stream>>>(hist, cursor);
    scatter_kernel<<<(N_EDGES_ + 255) / 256, 256, 0, stream>>>(row, col, cursor, row_s, col_s);

    // h_node = atom_table[z] @ atom_w + atom_b  (bf16 state)
    row_gemm_bf_kernel<1, 0, 0><<<grid_rows, 256, 0, stream>>>(
        atom_table, z, atom_w, atom_b, h_node_bf, N_NODES_);
    edge_embed_kernel<<<1024, 256, 0, stream>>>(pos, row_s, col_s, edge_emb_w, edge_emb_b, h_edge, N_EDGES_);
    pack_w_kernel<<<200, 256, 0, stream>>>(edge_w0, edge_w, Wp);

    for (int l = 0; l < NLAYER_; ++l) {
        (void)hipMemsetAsync(aggb, 0, (size_t)N_NODES_ * EMB * sizeof(float), stream);
        edge_mlp_sorted_kernel<<<N_EDGES_ / 64, 256, 0, stream>>>(
            h_node_bf, h_edge, aggb, row_s, col_s,
            Wp + (size_t)l * 114688,
            edge_b0 + (size_t)l * 128, edge_b + (size_t)l * 4 * 128);
        row_gemm_bf_kernel<0, 1, 1><<<grid_rows, 256, 0, stream>>>(
            aggb, nullptr, node_w + (size_t)l * 128 * 128, node_b + (size_t)l * 128,
            h_node_bf, N_NODES_);
    }

    (void)hipMemsetAsync(sums, 0, ((size_t)N_GRAPH_ * EMB + N_GRAPH_) * sizeof(float), stream);
    pool_kernel<<<(N_NODES_ + 255) / 256, 128, 0, stream>>>(h_node_bf, batch, sums, cnt, N_NODES_);
    final_kernel<<<1, 256, 0, stream>>>(sums, cnt, out_w, out_b, (float*)d_out);
}

// Round 8
// 2998.225 us; speedup vs baseline: 1.1895x; 1.0805x over previous
//
#include <hip/hip_runtime.h>

#define EMB      128
#define N_NODES_ 50000
#define N_EDGES_ 800000
#define N_GRAPH_ 256
#define NLAYER_  5

typedef short short8 __attribute__((ext_vector_type(8)));
typedef float floatx4 __attribute__((ext_vector_type(4)));

__device__ __forceinline__ float silu_f(float x) {
    return __fdividef(x, 1.0f + __expf(-x));   // exact-ish: v_exp + v_rcp
}
__device__ __forceinline__ float bf2f(unsigned short h) {
    return __uint_as_float(((unsigned)h) << 16);
}
__device__ __forceinline__ unsigned short f2bf(float f) {
    unsigned u = __float_as_uint(f);
    unsigned r = 0x7FFFu + ((u >> 16) & 1u);
    return (unsigned short)((u + r) >> 16);
}

// packed f32x2 -> bf16x2 (RNE). gfx950 has v_cvt_pk_bf16_f32.
#if defined(__has_builtin)
#if __has_builtin(__builtin_amdgcn_cvt_pk_bf16_f32)
#define HAVE_PK_BF16 1
#endif
#endif
#ifdef HAVE_PK_BF16
typedef __bf16 bf16x2 __attribute__((ext_vector_type(2)));
__device__ __forceinline__ unsigned f2bf_pk(float a, float b) {
    bf16x2 v = __builtin_amdgcn_cvt_pk_bf16_f32(a, b);
    unsigned u;
    __builtin_memcpy(&u, &v, 4);
    return u;
}
#else
__device__ __forceinline__ unsigned f2bf_pk(float a, float b) {
    return (unsigned)f2bf(a) | ((unsigned)f2bf(b) << 16);
}
#endif

// ---------------------------------------------------------------------------
// Edge sort by destination row: histogram -> 1-block scan -> atomic scatter.
// ---------------------------------------------------------------------------
__global__ __launch_bounds__(256) void hist_kernel(
    const int* __restrict__ row, int* __restrict__ hist)
{
    const int e = blockIdx.x * 256 + threadIdx.x;
    if (e < N_EDGES_) atomicAdd(&hist[row[e]], 1);
}

__global__ __launch_bounds__(256) void scan_kernel(
    const int* __restrict__ hist, int* __restrict__ cursor)
{
    __shared__ int ssum[256];
    const int tid = threadIdx.x;
    const int chunk = (N_NODES_ + 255) / 256;      // 196
    const int base = tid * chunk;
    int s = 0;
    for (int i = 0; i < chunk; ++i) {
        const int idx = base + i;
        if (idx < N_NODES_) s += hist[idx];
    }
    ssum[tid] = s;
    __syncthreads();
    for (int off = 1; off < 256; off <<= 1) {
        const int t2 = (tid >= off) ? ssum[tid - off] : 0;
        __syncthreads();
        ssum[tid] += t2;
        __syncthreads();
    }
    int run = ssum[tid] - s;
    for (int i = 0; i < chunk; ++i) {
        const int idx = base + i;
        if (idx < N_NODES_) { cursor[idx] = run; run += hist[idx]; }
    }
}

__global__ __launch_bounds__(256) void scatter_kernel(
    const int* __restrict__ row, const int* __restrict__ col,
    int* __restrict__ cursor, int* __restrict__ row_s, int* __restrict__ col_s)
{
    const int e = blockIdx.x * 256 + threadIdx.x;
    if (e >= N_EDGES_) return;
    const int r = row[e];
    const int p = atomicAdd(&cursor[r], 1);
    row_s[p] = r;
    col_s[p] = col[e];
}

// ---------------------------------------------------------------------------
// Weight packing: fp32 [K][128] -> bf16 fragment order. Under the operand
// swap this exact layout serves as the A-operand (W^T): lane lr = n_out,
// k = lg*8+j  ->  element W[kb*32+lg*8+j][t*16+lr].
// ---------------------------------------------------------------------------
__global__ __launch_bounds__(256) void pack_w_kernel(
    const float* __restrict__ edge_w0, const float* __restrict__ edge_w,
    unsigned short* __restrict__ Wp)
{
    const int bid = blockIdx.x;            // 200 = 5 layers * 5 stages * 8 tiles
    const int l = bid / 40, r = bid % 40, s = r / 8, t = r % 8;
    const int Kb = (s == 0) ? 12 : 4;
    const float* __restrict__ src = (s == 0)
        ? edge_w0 + (size_t)l * 384 * 128
        : edge_w  + ((size_t)l * 4 + (s - 1)) * 128 * 128;
    unsigned short* __restrict__ dst =
        Wp + (size_t)l * 114688 + ((s == 0) ? 0 : (49152 + (s - 1) * 16384)) + (size_t)t * Kb * 512;
    const int n = Kb * 512;
    for (int p = threadIdx.x; p < n; p += 256) {
        const int j = p & 7, lane = (p >> 3) & 63, kb = p >> 9;
        const int k  = kb * 32 + ((lane >> 4) << 3) + j;
        const int nn = t * 16 + (lane & 15);
        dst[p] = f2bf(src[(size_t)k * 128 + nn]);
    }
}

// ---------------------------------------------------------------------------
// SORTED-edge MFMA edge MLP, operand-swapped:
//   a-operand = weights (W^T tiles, global), b-operand = activations (LDS).
//   D[n_out][edge] -> each thread's 4 acc values are 4 consecutive LDS
//   columns of one row -> packed b64 writeback; bias pre-loaded into acc;
//   packed v_cvt_pk_bf16_f32 conversions; division-free addressing.
// ---------------------------------------------------------------------------
__global__ __launch_bounds__(256, 3) void edge_mlp_sorted_kernel(
    const unsigned short* __restrict__ h_node_bf, unsigned short* __restrict__ h_edge,
    float* __restrict__ agg,
    const int* __restrict__ row_s, const int* __restrict__ col_s,
    const unsigned short* __restrict__ Wp,
    const float* __restrict__ b0, const float* __restrict__ bh)
{
    __shared__ __align__(16) unsigned short A[64][392];   // 50,176 B
    __shared__ int rv[64], cv[64];
    const int tid = threadIdx.x;
    const int e0 = blockIdx.x * 64;

    if (tid < 64) { rv[tid] = row_s[e0 + tid]; cv[tid] = col_s[e0 + tid]; }
    __syncthreads();

    // staging: thread owns row t = tid>>2, chunks (tid&3)+4i — no division,
    // 4 lanes cover one 64B line per iteration.
    {
        const int t = tid >> 2, q = tid & 3;
        const unsigned short* pe = &h_edge[(size_t)(e0 + t) * 128];
        const unsigned short* pr = &h_node_bf[(size_t)rv[t] * 128];
        const unsigned short* pc = &h_node_bf[(size_t)cv[t] * 128];
#pragma unroll
        for (int i = 0; i < 12; ++i) {
            const int ch = q + 4 * i;          // 0..47 (branches fold per i)
            const int k8 = ch << 3;
            const unsigned short* src = (ch < 16) ? (pe + k8)
                                      : (ch < 32) ? (pr + (k8 - 128))
                                                  : (pc + (k8 - 256));
            *(short8*)&A[t][k8] = *(const short8*)src;
        }
    }
    __syncthreads();

    const int lane = tid & 63;
    const int wv   = tid >> 6;
    const int lr   = lane & 15;   // b-frag: edge-in-tile | a-frag: n_out-in-tile
    const int lg   = lane >> 4;
    const int nt0  = 2 * wv, nt1 = nt0 + 1;

    for (int s = 0; s < 5; ++s) {
        const int Kb = (s == 0) ? 12 : 4;
        const unsigned short* __restrict__ Ws =
            Wp + ((s == 0) ? 0 : (49152 + (s - 1) * 16384));
        const float* __restrict__ bias = (s == 0) ? b0 : (bh + (s - 1) * 128);

        // bias pre-loaded into accumulators (D = W^T·M + bias)
        const float4 bv0 = *(const float4*)&bias[nt0 * 16 + lg * 4];
        const float4 bv1 = *(const float4*)&bias[nt1 * 16 + lg * 4];
        floatx4 acc0[4], acc1[4];
#pragma unroll
        for (int et = 0; et < 4; ++et) {
            acc0[et] = (floatx4){bv0.x, bv0.y, bv0.z, bv0.w};
            acc1[et] = (floatx4){bv1.x, bv1.y, bv1.z, bv1.w};
        }

        const unsigned short* aptr0 = Ws + ((size_t)(nt0 * Kb) * 64 + lane) * 8;
        const unsigned short* aptr1 = Ws + ((size_t)(nt1 * Kb) * 64 + lane) * 8;
#pragma unroll 2
        for (int kb = 0; kb < Kb; ++kb) {
            const short8 wf0 = *(const short8*)(aptr0 + (size_t)kb * 512);
            const short8 wf1 = *(const short8*)(aptr1 + (size_t)kb * 512);
#pragma unroll
            for (int et = 0; et < 4; ++et) {
                const short8 mf = *(const short8*)&A[et * 16 + lr][kb * 32 + lg * 8];
                acc0[et] = __builtin_amdgcn_mfma_f32_16x16x32_bf16(wf0, mf, acc0[et], 0, 0, 0);
                acc1[et] = __builtin_amdgcn_mfma_f32_16x16x32_bf16(wf1, mf, acc1[et], 0, 0, 0);
            }
        }
        __syncthreads();   // all LDS reads of this stage done before overwrite
#pragma unroll
        for (int et = 0; et < 4; ++et) {
            uint2 p0, p1;
            p0.x = f2bf_pk(silu_f(acc0[et][0]), silu_f(acc0[et][1]));
            p0.y = f2bf_pk(silu_f(acc0[et][2]), silu_f(acc0[et][3]));
            p1.x = f2bf_pk(silu_f(acc1[et][0]), silu_f(acc1[et][1]));
            p1.y = f2bf_pk(silu_f(acc1[et][2]), silu_f(acc1[et][3]));
            *(uint2*)&A[et * 16 + lr][nt0 * 16 + lg * 4] = p0;
            *(uint2*)&A[et * 16 + lr][nt1 * 16 + lg * 4] = p1;
        }
        __syncthreads();
    }

    // phase 1: h_edge_new = old + m; store global + back to LDS (packed)
    {
        const int t = tid >> 2, q = tid & 3;
        unsigned short* pe = &h_edge[(size_t)(e0 + t) * 128];
#pragma unroll
        for (int i = 0; i < 4; ++i) {
            const int k8 = (q + 4 * i) << 3;
            const short8 mv = *(const short8*)&A[t][k8];
            const short8 ov = *(const short8*)(pe + k8);
            float he[8];
#pragma unroll
            for (int j = 0; j < 8; ++j)
                he[j] = bf2f((unsigned short)ov[j]) + bf2f((unsigned short)mv[j]);
            uint4 sv;
            sv.x = f2bf_pk(he[0], he[1]);
            sv.y = f2bf_pk(he[2], he[3]);
            sv.z = f2bf_pk(he[4], he[5]);
            sv.w = f2bf_pk(he[6], he[7]);
            *(uint4*)(pe + k8) = sv;
            *(uint4*)&A[t][k8] = sv;
        }
    }
    __syncthreads();

    // phase 2: run-length merged scatter atomics (lane-consecutive flushes)
    {
        const int c    = tid & 127;
        const int half = tid >> 7;
        const int tstart = half * 32;
        int curRow = rv[tstart];
        float accv = 0.f;
#pragma unroll 8
        for (int t = tstart; t < tstart + 32; ++t) {
            const int rr = rv[t];
            const float v = bf2f(A[t][c]);
            if (rr != curRow) {
                atomicAdd(&agg[(size_t)curRow * 128 + c], accv);
                accv = 0.f;
                curRow = rr;
            }
            accv += v;
        }
        atomicAdd(&agg[(size_t)curRow * 128 + c], accv);
    }
}

// ---------------------------------------------------------------------------
// Row GEMM with bf16 node state (gather / silu / residual variants).
// ---------------------------------------------------------------------------
__device__ __forceinline__ void fma4x4(const float4 a[4], const float4& w0, const float4& w1,
                                       const float4& w2, const float4& w3, float acc[4][4]) {
#pragma unroll
    for (int i = 0; i < 4; ++i) {
        acc[i][0] = fmaf(a[i].x, w0.x, fmaf(a[i].y, w1.x, fmaf(a[i].z, w2.x, fmaf(a[i].w, w3.x, acc[i][0]))));
        acc[i][1] = fmaf(a[i].x, w0.y, fmaf(a[i].y, w1.y, fmaf(a[i].z, w2.y, fmaf(a[i].w, w3.y, acc[i][1]))));
        acc[i][2] = fmaf(a[i].x, w0.z, fmaf(a[i].y, w1.z, fmaf(a[i].z, w2.z, fmaf(a[i].w, w3.z, acc[i][2]))));
        acc[i][3] = fmaf(a[i].x, w0.w, fmaf(a[i].y, w1.w, fmaf(a[i].z, w2.w, fmaf(a[i].w, w3.w, acc[i][3]))));
    }
}

template <int GATHER, int RESID, int SILU>
__global__ __launch_bounds__(256, 4) void row_gemm_bf_kernel(
    const float* __restrict__ src, const int* __restrict__ gidx,
    const float* __restrict__ W, const float* __restrict__ bias,
    unsigned short* __restrict__ dst, int N)
{
    __shared__ __align__(16) float A[32][132];
    const int tid = threadIdx.x;
    const int n0 = blockIdx.x * 32;

    for (int idx = tid; idx < 32 * 32; idx += 256) {
        int t = idx >> 5, k = (idx & 31) << 2;
        int n = n0 + t;
        float4 v = make_float4(0.f, 0.f, 0.f, 0.f);
        if (n < N) {
            int rr = GATHER ? gidx[n] : n;
            v = *(const float4*)&src[(size_t)rr * 128 + k];
        }
        *(float4*)&A[t][k] = v;
    }
    __syncthreads();

    const int r = tid >> 5, c = tid & 31;
    const int t0 = r << 2, j0 = c << 2;
    float acc[4][4] = {{0.f, 0.f, 0.f, 0.f}};
#pragma unroll 2
    for (int kk = 0; kk < 128; kk += 4) {
        float4 a[4];
#pragma unroll
        for (int i = 0; i < 4; ++i) a[i] = *(const float4*)&A[t0 + i][kk];
        const float4 w0 = *(const float4*)&W[(size_t)(kk + 0) * 128 + j0];
        const float4 w1 = *(const float4*)&W[(size_t)(kk + 1) * 128 + j0];
        const float4 w2 = *(const float4*)&W[(size_t)(kk + 2) * 128 + j0];
        const float4 w3 = *(const float4*)&W[(size_t)(kk + 3) * 128 + j0];
        fma4x4(a, w0, w1, w2, w3, acc);
    }
    const float4 bv = *(const float4*)&bias[j0];
    const float bias4[4] = {bv.x, bv.y, bv.z, bv.w};
#pragma unroll
    for (int i = 0; i < 4; ++i) {
        int n = n0 + t0 + i;
        if (n >= N) continue;
        float x[4];
#pragma unroll
        for (int jj = 0; jj < 4; ++jj) {
            x[jj] = acc[i][jj] + bias4[jj];
            if (SILU) x[jj] = silu_f(x[jj]);
        }
        const size_t off = (size_t)n * 128 + j0;
        if (RESID) {
            const ushort4 d = *(const ushort4*)&dst[off];
            x[0] += bf2f(d.x); x[1] += bf2f(d.y); x[2] += bf2f(d.z); x[3] += bf2f(d.w);
        }
        uint2 p;
        p.x = f2bf_pk(x[0], x[1]);
        p.y = f2bf_pk(x[2], x[3]);
        *(uint2*)&dst[off] = p;
    }
}

// ---------------------------------------------------------------------------
// Edge embedding (on sorted edge lists).
// ---------------------------------------------------------------------------
__global__ __launch_bounds__(256) void edge_embed_kernel(
    const float* __restrict__ pos, const int* __restrict__ row, const int* __restrict__ col,
    const float* __restrict__ Wemb, const float* __restrict__ bemb,
    unsigned short* __restrict__ h_edge, int E)
{
    __shared__ __align__(16) float Ws[32][128];
    __shared__ float bas[8][32];
    const int tid = threadIdx.x;
    {
        const float4* Wv = (const float4*)Wemb;
        float4* Wsv = (float4*)Ws;
        for (int idx = tid; idx < 1024; idx += 256) Wsv[idx] = Wv[idx];
    }
    const int g = tid >> 5, k = tid & 31;
    const int j = tid & 127, gh = tid >> 7;
    const float mu   = (float)k * (5.0f / 31.0f);
    const float invs = 32.0f / 5.0f;

    for (int eb = blockIdx.x * 8; eb < E; eb += gridDim.x * 8) {
        __syncthreads();
        const int e = eb + g;
        const int rr = row[e], cc = col[e];
        const float dx = pos[rr * 3 + 0] - pos[cc * 3 + 0];
        const float dy = pos[rr * 3 + 1] - pos[cc * 3 + 1];
        const float dz = pos[rr * 3 + 2] - pos[cc * 3 + 2];
        const float d = sqrtf(dx * dx + dy * dy + dz * dz);
        const float t = (d - mu) * invs;
        bas[g][k] = __expf(-0.5f * t * t);
        __syncthreads();
#pragma unroll
        for (int gg = 0; gg < 4; ++gg) {
            const int ge = (gh << 2) + gg;
            float h = bemb[j];
#pragma unroll
            for (int kk = 0; kk < 32; ++kk) h = fmaf(bas[ge][kk], Ws[kk][j], h);
            h_edge[(size_t)(eb + ge) * 128 + j] = f2bf(h);
        }
    }
}

// ---------------------------------------------------------------------------
// Graph pooling (bf16 node state) + output head.
// ---------------------------------------------------------------------------
__global__ __launch_bounds__(128) void pool_kernel(
    const unsigned short* __restrict__ h_node_bf, const int* __restrict__ batch,
    float* __restrict__ sums, float* __restrict__ cnt, int N)
{
    __shared__ int bb[256];
    const int tid = threadIdx.x;
    const int n0 = blockIdx.x * 256;
    for (int idx = tid; idx < 256; idx += 128) {
        int n = n0 + idx;
        bb[idx] = (n < N) ? batch[n] : -1;
    }
    __syncthreads();
    int cur = bb[0];
    float run = 0.f, runc = 0.f;
    for (int i = 0; i < 256; ++i) {
        const int b = bb[i];
        if (b < 0) break;
        if (b != cur) {
            atomicAdd(&sums[(size_t)cur * 128 + tid], run);
            if (tid == 0) atomicAdd(&cnt[cur], runc);
            run = 0.f; runc = 0.f; cur = b;
        }
        run += bf2f(h_node_bf[(size_t)(n0 + i) * 128 + tid]);
        runc += 1.f;
    }
    atomicAdd(&sums[(size_t)cur * 128 + tid], run);
    if (tid == 0) atomicAdd(&cnt[cur], runc);
}

__global__ __launch_bounds__(256) void final_kernel(
    const float* __restrict__ sums, const float* __restrict__ cnt,
    const float* __restrict__ out_w, const float* __restrict__ out_b,
    float* __restrict__ out)
{
    const int g = threadIdx.x;
    const float c = fmaxf(cnt[g], 1.0f);
    float acc = 0.f;
    for (int jj = 0; jj < 128; ++jj) acc = fmaf(sums[(size_t)g * 128 + jj], out_w[jj], acc);
    out[g] = acc / c + out_b[0];
}

__global__ void zero_out_kernel(float* out, int n) {
    int i = blockIdx.x * 256 + threadIdx.x;
    if (i < n) out[i] = 0.f;
}

// ---------------------------------------------------------------------------

extern "C" void kernel_launch(void* const* d_in, const int* in_sizes, int n_in,
                              void* d_out, int out_size, void* d_ws, size_t ws_size,
                              hipStream_t stream)
{
    const int*   z          = (const int*)  d_in[0];
    const float* pos        = (const float*)d_in[1];
    const int*   batch      = (const int*)  d_in[2];
    const int*   eidx       = (const int*)  d_in[3];
    const float* atom_table = (const float*)d_in[4];
    const float* atom_w     = (const float*)d_in[5];
    const float* atom_b     = (const float*)d_in[6];
    const float* edge_emb_w = (const float*)d_in[7];
    const float* edge_emb_b = (const float*)d_in[8];
    const float* edge_w0    = (const float*)d_in[9];
    const float* edge_b0    = (const float*)d_in[10];
    const float* edge_w     = (const float*)d_in[11];
    const float* edge_b     = (const float*)d_in[12];
    const float* node_w     = (const float*)d_in[13];
    const float* node_b     = (const float*)d_in[14];
    const float* out_w      = (const float*)d_in[15];
    const float* out_b      = (const float*)d_in[16];
    const int* row = eidx;
    const int* col = eidx + N_EDGES_;

    // ws layout (251.28 MB total):
    // agg f32 | sums f32 | cnt f32 | h_node bf16 | h_edge bf16 | Wp bf16 |
    // hist | cursor | row_s | col_s
    float* aggb = (float*)d_ws;
    float* sums = aggb + (size_t)N_NODES_ * EMB;
    float* cnt  = sums + (size_t)N_GRAPH_ * EMB;
    unsigned short* h_node_bf = (unsigned short*)(cnt + N_GRAPH_);
    unsigned short* h_edge    = h_node_bf + (size_t)N_NODES_ * EMB;
    unsigned short* Wp        = h_edge + (size_t)N_EDGES_ * EMB;
    int* hist   = (int*)(Wp + (size_t)NLAYER_ * 114688);
    int* cursor = hist + N_NODES_;
    int* row_s  = cursor + N_NODES_;
    int* col_s  = row_s + N_EDGES_;

    const size_t need = ((size_t)(N_NODES_ * EMB + N_GRAPH_ * EMB + N_GRAPH_)) * 4
                      + ((size_t)N_NODES_ * EMB + (size_t)N_EDGES_ * EMB + (size_t)NLAYER_ * 114688) * 2
                      + ((size_t)N_NODES_ * 2 + (size_t)N_EDGES_ * 2) * 4;

    if (ws_size < need) {
        zero_out_kernel<<<1, 256, 0, stream>>>((float*)d_out, N_GRAPH_);
        return;
    }

    const int grid_rows = (N_NODES_ + 31) / 32;

    (void)hipMemsetAsync(hist, 0, N_NODES_ * sizeof(int), stream);
    hist_kernel<<<(N_EDGES_ + 255) / 256, 256, 0, stream>>>(row, hist);
    scan_kernel<<<1, 256, 0, stream>>>(hist, cursor);
    scatter_kernel<<<(N_EDGES_ + 255) / 256, 256, 0, stream>>>(row, col, cursor, row_s, col_s);

    row_gemm_bf_kernel<1, 0, 0><<<grid_rows, 256, 0, stream>>>(
        atom_table, z, atom_w, atom_b, h_node_bf, N_NODES_);
    edge_embed_kernel<<<1024, 256, 0, stream>>>(pos, row_s, col_s, edge_emb_w, edge_emb_b, h_edge, N_EDGES_);
    pack_w_kernel<<<200, 256, 0, stream>>>(edge_w0, edge_w, Wp);

    for (int l = 0; l < NLAYER_; ++l) {
        (void)hipMemsetAsync(aggb, 0, (size_t)N_NODES_ * EMB * sizeof(float), stream);
        edge_mlp_sorted_kernel<<<N_EDGES_ / 64, 256, 0, stream>>>(
            h_node_bf, h_edge, aggb, row_s, col_s,
            Wp + (size_t)l * 114688,
            edge_b0 + (size_t)l * 128, edge_b + (size_t)l * 4 * 128);
        row_gemm_bf_kernel<0, 1, 1><<<grid_rows, 256, 0, stream>>>(
            aggb, nullptr, node_w + (size_t)l * 128 * 128, node_b + (size_t)l * 128,
            h_node_bf, N_NODES_);
    }

    (void)hipMemsetAsync(sums, 0, ((size_t)N_GRAPH_ * EMB + N_GRAPH_) * sizeof(float), stream);
    pool_kernel<<<(N_NODES_ + 255) / 256, 128, 0, stream>>>(h_node_bf, batch, sums, cnt, N_NODES_);
    final_kernel<<<1, 256, 0, stream>>>(sums, cnt, out_w, out_b, (float*)d_out);
}